// Round 7
// baseline (86.737 us; speedup 1.0000x reference)
//
#include <hip/hip_runtime.h>
#include <hip/hip_bf16.h>

#define NV 100       // n_vars
#define HID 64       // hidden
#define NE 1000      // experts
#define NB 4096      // batch
#define ESPLIT 32    // K-split count
#define BLOB 4096    // u32 per expert blob: [0,3584) W2 frags, [3584,3648) W1 f32,
                     // [3648,3712) b1 f32, [3712,4096) pad (staged, never read)

typedef __attribute__((ext_vector_type(8))) short short8;   // MFMA A/B frag
typedef __attribute__((ext_vector_type(4))) float f32x4;    // MFMA C/D frag

__device__ __align__(16) float g_bsum[NV];

// one-instruction RNE f32->bf16 (v_cvt path)
__device__ __forceinline__ short cvtbf(float f) {
    return __builtin_bit_cast(short, (__bf16)f);
}
__device__ __forceinline__ unsigned short f2bf(float f) {
    return (unsigned short)__builtin_bit_cast(short, (__bf16)f);
}
__device__ __forceinline__ float bf2f(unsigned short s) {
    union { unsigned u; float f; } v; v.u = ((unsigned)s) << 16;
    return v.f;
}
__device__ __forceinline__ unsigned pkbf(float a, float b) {
    return (unsigned)f2bf(a) | ((unsigned)f2bf(b) << 16);
}

// balanced, 4-aligned expert split: 26 splits of 32, 6 splits of 28
__device__ __host__ __forceinline__ void esplit_range(int ks, int* pe0, int* pne) {
    int e0 = (ks < 26) ? 32 * ks : 832 + 28 * (ks - 26);
    int ne = (ks < 26) ? 32 : 28;
    *pe0 = e0; *pne = ne;
}

// ---------------- bias: g_bsum[v] = sum_e b2[e*NV + v] ----------------
__global__ void bias_kernel(const float* __restrict__ b2) {
    int v = blockIdx.x;
    float s = 0.f;
    for (int e = threadIdx.x; e < NE; e += 256)
        s += b2[e * NV + v];
    __shared__ float red[4];
    for (int off = 32; off; off >>= 1) s += __shfl_down(s, off, 64);
    if ((threadIdx.x & 63) == 0) red[threadIdx.x >> 6] = s;
    __syncthreads();
    if (threadIdx.x == 0) g_bsum[v] = red[0] + red[1] + red[2] + red[3];
}

// ---------------- init (fallback path only) ----------------
__global__ void init_kernel(float* __restrict__ out) {
    int idx = blockIdx.x * 256 + threadIdx.x;
    if (idx < NB * NV) out[idx] = g_bsum[idx % NV];
}

// ---------------- prepass: per-expert 16 KiB blob ----------------
// W2 frag f = ksh*7+t (1 KiB each): u32 at (f*256 + l*4 + q) holds
// pk(W2[h0][v], W2[h0+1][v]), l=kg*16+lrow, h0=ksh*32+kg*8+2q, v=t*16+lrow.
// Hot read = ds_read_b128 at f*1024 + lane*16 (linear, conflict-free).
// W1/b1 appended as f32 so the hot loop has zero unpack VALU.
__global__ void prepass4(const float* __restrict__ W2, const float* __restrict__ W1,
                         const float* __restrict__ b1, unsigned* __restrict__ blob) {
    __shared__ float t[HID][NV + 1];
    int e = blockIdx.x;
    const float* src = W2 + (size_t)e * (HID * NV);
    for (int i = threadIdx.x; i < HID * NV; i += 256) {
        int hh = i / NV;
        int v = i - hh * NV;
        t[hh][v] = src[i];
    }
    __syncthreads();
    unsigned* dst = blob + (size_t)e * BLOB;
    for (int o = threadIdx.x; o < 3584; o += 256) {
        int f = o >> 8;          // 0..13
        int r = o & 255;
        int l = r >> 2;          // lane
        int q = r & 3;           // u32 within 16B chunk
        int ksh = f / 7, tt = f - 7 * ksh;
        int kg = l >> 4, lrow = l & 15;
        int h0 = ksh * 32 + kg * 8 + 2 * q;
        int v = tt * 16 + lrow;
        unsigned val = 0;
        if (v < NV) val = pkbf(t[h0][v], t[h0 + 1][v]);
        dst[o] = val;
    }
    if (threadIdx.x < 64) {
        dst[3584 + threadIdx.x] = __builtin_bit_cast(unsigned, W1[(size_t)e * HID + threadIdx.x]);
        dst[3648 + threadIdx.x] = __builtin_bit_cast(unsigned, b1[(size_t)e * HID + threadIdx.x]);
    }
}

// ---------------- main: 4 waves x 64 rows, 3-buf counted-vmcnt pipeline ----------------
__global__ __launch_bounds__(256, 2) void moe7(
    const float* __restrict__ x, const unsigned* __restrict__ blob,
    float* __restrict__ part)
{
    __shared__ __align__(16) unsigned char smem[65536];
    // [0, 49152): 3 x 16 KiB expert blobs
    unsigned short* xts = (unsigned short*)(smem + 49152);   // [32][256] bf16 x^T

    const int bid = blockIdx.x;
    const int xcd = bid & 7;
    const int jj  = bid >> 3;              // 0..63
    const int ks  = xcd * 4 + (jj & 3);    // 4 consecutive ksplits per XCD (L2 locality)
    const int mb  = jj >> 2;               // 0..15

    const int tid  = threadIdx.x;
    const int lane = tid & 63;
    const int wave = tid >> 6;             // 0..3, owns rows wave*64 .. +63
    const int lrow = lane & 15;
    const int kg   = lane >> 4;

    const int row0 = mb * 256;
    int e0, ne; esplit_range(ks, &e0, &ne);

    // ---- stage: one 16 KiB blob -> LDS, 4 uniform gload_lds(16B) per thread ----
    auto stage = [&](int buf, int e) {
        const unsigned* g = blob + (size_t)e * BLOB;
        unsigned* lbase = (unsigned*)(smem + buf * 16384);
        #pragma unroll
        for (int k = 0; k < 4; ++k) {
            int off = (k * 256 + tid) * 4;   // u32 index of 16B chunk
            __builtin_amdgcn_global_load_lds(
                (const __attribute__((address_space(1))) unsigned*)(g + off),
                (__attribute__((address_space(3))) unsigned*)(lbase + off),
                16, 0, 0);
        }
    };

    // prologue: prefetch blobs 0,1 then stage x tile; one full drain
    stage(0, e0);
    stage(1, e0 + 1);
    {
        const float* xp = x + (size_t)(row0 + tid) * NE + e0;
        #pragma unroll
        for (int c4 = 0; c4 < 8; ++c4) {
            int eb = c4 * 4;
            if (eb < ne) {
                float4 v = *(const float4*)(xp + eb);
                xts[(eb + 0) * 256 + tid] = f2bf(v.x);
                xts[(eb + 1) * 256 + tid] = f2bf(v.y);
                xts[(eb + 2) * 256 + tid] = f2bf(v.z);
                xts[(eb + 3) * 256 + tid] = f2bf(v.w);
            }
        }
    }
    __syncthreads();   // drains everything once; bufs 0,1 + xts ready

    f32x4 acc[4][7];
    #pragma unroll
    for (int rf = 0; rf < 4; ++rf)
        #pragma unroll
        for (int t = 0; t < 7; ++t)
            acc[rf][t] = (f32x4){0.f, 0.f, 0.f, 0.f};

    int bi = 0;  // buffer of current expert
    for (int ei = 0; ei < ne; ++ei) {
        // buf bi's 4 loads are the oldest outstanding; keep newer 4 in flight.
        asm volatile("s_waitcnt vmcnt(4)" ::: "memory");
        __builtin_amdgcn_s_barrier();            // all waves: buf bi ready AND prev expert done
        __builtin_amdgcn_sched_barrier(0);       // no LDS reads hoist above this point

        // stage expert ei+2 into buffer (bi+2)%3 — its previous user (ei-1) just finished
        if (ei + 2 < ne) {
            int b2 = bi + 2; if (b2 >= 3) b2 -= 3;
            stage(b2, e0 + ei + 2);
        }

        const unsigned char* buf = smem + bi * 16384;
        const float* w1p = (const float*)(buf + 14336);
        const float* b1p = (const float*)(buf + 14592);

        float xv[4];
        #pragma unroll
        for (int rf = 0; rf < 4; ++rf)
            xv[rf] = bf2f(xts[ei * 256 + wave * 64 + rf * 16 + lrow]);

        #pragma unroll
        for (int ksh = 0; ksh < 2; ++ksh) {
            const int hb = ksh * 32 + kg * 8;
            float4 wa = *(const float4*)(w1p + hb);
            float4 wb = *(const float4*)(w1p + hb + 4);
            float4 ba = *(const float4*)(b1p + hb);
            float4 bb = *(const float4*)(b1p + hb + 4);

            short8 afr[4];
            #pragma unroll
            for (int rf = 0; rf < 4; ++rf) {
                float xr = xv[rf];
                short8 a;
                a[0] = cvtbf(fmaxf(fmaf(xr, wa.x, ba.x), 0.f));
                a[1] = cvtbf(fmaxf(fmaf(xr, wa.y, ba.y), 0.f));
                a[2] = cvtbf(fmaxf(fmaf(xr, wa.z, ba.z), 0.f));
                a[3] = cvtbf(fmaxf(fmaf(xr, wa.w, ba.w), 0.f));
                a[4] = cvtbf(fmaxf(fmaf(xr, wb.x, bb.x), 0.f));
                a[5] = cvtbf(fmaxf(fmaf(xr, wb.y, bb.y), 0.f));
                a[6] = cvtbf(fmaxf(fmaf(xr, wb.z, bb.z), 0.f));
                a[7] = cvtbf(fmaxf(fmaf(xr, wb.w, bb.w), 0.f));
                afr[rf] = a;
            }

            __builtin_amdgcn_s_setprio(1);
            #pragma unroll
            for (int t = 0; t < 7; ++t) {
                // frag-contiguous: one linear ds_read_b128 feeds 4 MFMAs
                short8 bf = *(const short8*)(buf + ((ksh * 7 + t) << 10) + lane * 16);
                #pragma unroll
                for (int rf = 0; rf < 4; ++rf)
                    acc[rf][t] = __builtin_amdgcn_mfma_f32_16x16x32_bf16(afr[rf], bf, acc[rf][t], 0, 0, 0);
            }
            __builtin_amdgcn_s_setprio(0);
        }
        __builtin_amdgcn_sched_barrier(0);       // compute stays inside its phase
        bi = (bi + 1 == 3) ? 0 : bi + 1;
    }

    // epilogue: C/D layout col = lane&15, row = kg*4 + reg -> partials
    float* dst = part + (size_t)ks * (NB * NV);
    #pragma unroll
    for (int rf = 0; rf < 4; ++rf) {
        #pragma unroll
        for (int t = 0; t < 7; ++t) {
            int col = t * 16 + lrow;
            if (col < NV) {
                size_t base = (size_t)(row0 + wave * 64 + rf * 16 + kg * 4) * NV + col;
                #pragma unroll
                for (int r = 0; r < 4; ++r)
                    dst[base + (size_t)r * NV] = acc[rf][t][r];
            }
        }
    }
}

// ---------------- reduce: out = bias + sum_k part[k] (float4) ----------------
__global__ void reduce2(const float* __restrict__ part, float* __restrict__ out) {
    int i4 = blockIdx.x * 256 + threadIdx.x;   // < NB*NV/4 = 102400
    f32x4 s = *(const f32x4*)&g_bsum[(i4 % 25) * 4];
    size_t off = (size_t)i4 * 4;
    #pragma unroll 4
    for (int k = 0; k < ESPLIT; ++k)
        s += *(const f32x4*)&part[(size_t)k * (NB * NV) + off];
    *(f32x4*)&out[off] = s;
}

// ---------------- fallback (tiny ws): in-kernel convert + atomics ----------------
#define LDW 72
__global__ __launch_bounds__(256, 3) void moe_fallback(
    const float* __restrict__ x, const float* __restrict__ W1,
    const float* __restrict__ b1, const float* __restrict__ W2,
    float* __restrict__ dst)
{
    __shared__ unsigned short w2t[8192];
    const int tid  = threadIdx.x;
    const int lane = tid & 63;
    const int lrow = lane & 15;
    const int kg   = lane >> 4;
    const int wave = tid >> 6;
    const int row0 = blockIdx.x * 128 + wave * 32;
    const int e0 = blockIdx.y * 32;
    const int e1 = min(NE, e0 + 32);

    f32x4 acc[2][7];
    #pragma unroll
    for (int rf = 0; rf < 2; ++rf)
        #pragma unroll
        for (int t = 0; t < 7; ++t)
            acc[rf][t] = (f32x4){0.f, 0.f, 0.f, 0.f};

    const float* xr0 = x + (size_t)(row0 + lrow) * NE;
    const float* xr1 = x + (size_t)(row0 + 16 + lrow) * NE;

    for (int e = e0; e < e1; ++e) {
        __syncthreads();
        const float* src = W2 + (size_t)e * (HID * NV);
        unsigned* w2t32 = (unsigned*)w2t;
        #pragma unroll
        for (int k = 0; k < 13; ++k) {
            int i = tid + k * 256;
            if (i < (HID / 2) * NV) {
                int a3  = i / 400;
                int rem = i - a3 * 400;
                int bv  = rem >> 2;
                int c   = rem & 3;
                int hh2 = a3 * 4 + c;
                float f0 = src[(2 * hh2) * NV + bv];
                float f1 = src[(2 * hh2 + 1) * NV + bv];
                w2t32[bv * (LDW / 2) + hh2] = pkbf(f0, f1);
            }
        }
        __syncthreads();

        float xv0 = xr0[e];
        float xv1 = xr1[e];
        const float* w1p = W1 + e * HID;
        const float* b1p = b1 + e * HID;
        #pragma unroll
        for (int ksh = 0; ksh < 2; ++ksh) {
            const int hb = ksh * 32 + kg * 8;
            f32x4 w1lo = *(const f32x4*)(w1p + hb);
            f32x4 w1hi = *(const f32x4*)(w1p + hb + 4);
            f32x4 blo  = *(const f32x4*)(b1p + hb);
            f32x4 bhi  = *(const f32x4*)(b1p + hb + 4);
            short8 a0, a1;
            #pragma unroll
            for (int j = 0; j < 4; ++j) {
                a0[j]     = cvtbf(fmaxf(fmaf(xv0, w1lo[j], blo[j]), 0.f));
                a0[j + 4] = cvtbf(fmaxf(fmaf(xv0, w1hi[j], bhi[j]), 0.f));
                a1[j]     = cvtbf(fmaxf(fmaf(xv1, w1lo[j], blo[j]), 0.f));
                a1[j + 4] = cvtbf(fmaxf(fmaf(xv1, w1hi[j], bhi[j]), 0.f));
            }
            #pragma unroll
            for (int t = 0; t < 7; ++t) {
                short8 bf = *(const short8*)&w2t[(t * 16 + lrow) * LDW + hb];
                acc[0][t] = __builtin_amdgcn_mfma_f32_16x16x32_bf16(a0, bf, acc[0][t], 0, 0, 0);
                acc[1][t] = __builtin_amdgcn_mfma_f32_16x16x32_bf16(a1, bf, acc[1][t], 0, 0, 0);
            }
        }
    }

    #pragma unroll
    for (int rf = 0; rf < 2; ++rf) {
        #pragma unroll
        for (int t = 0; t < 7; ++t) {
            int col = t * 16 + lrow;
            if (col < NV) {
                size_t base = (size_t)(row0 + rf * 16 + kg * 4) * NV + col;
                #pragma unroll
                for (int r = 0; r < 4; ++r)
                    atomicAdd(&dst[base + (size_t)r * NV], acc[rf][t][r]);
            }
        }
    }
}

extern "C" void kernel_launch(void* const* d_in, const int* in_sizes, int n_in,
                              void* d_out, int out_size, void* d_ws, size_t ws_size,
                              hipStream_t stream) {
    const float* x  = (const float*)d_in[0];
    const float* W1 = (const float*)d_in[1];
    const float* b1 = (const float*)d_in[2];
    const float* W2 = (const float*)d_in[3];
    const float* b2 = (const float*)d_in[4];
    float* out = (float*)d_out;

    const size_t BLOB_BYTES = (size_t)NE * BLOB * 4;         // 16,384,000
    const size_t PART_BYTES = (size_t)ESPLIT * NB * NV * 4;  // 52,428,800

    bias_kernel<<<NV, 256, 0, stream>>>(b2);

    if (ws_size >= BLOB_BYTES + PART_BYTES) {
        unsigned* blob = (unsigned*)d_ws;
        float* part = (float*)((char*)d_ws + BLOB_BYTES);
        prepass4<<<NE, 256, 0, stream>>>(W2, W1, b1, blob);
        moe7<<<512, 256, 0, stream>>>(x, blob, part);
        reduce2<<<(NB * NV / 4 + 255) / 256, 256, 0, stream>>>(part, out);
    } else {
        init_kernel<<<(NB * NV + 255) / 256, 256, 0, stream>>>(out);
        moe_fallback<<<dim3(NB / 128, ESPLIT), 256, 0, stream>>>(x, W1, b1, W2, out);
    }
}